// Round 2
// baseline (401.272 us; speedup 1.0000x reference)
//
#include <hip/hip_runtime.h>
#include <math.h>

#define NB   32768
#define NM   2048
#define NEMB 128
#define NK   8
#define TAU  0.3f
#define FLT_BIG 3.402823466e38f

typedef __attribute__((ext_vector_type(8))) short bf16x8;
typedef __attribute__((ext_vector_type(4))) float f32x4;

__device__ __forceinline__ float gelu_exact(float x) {
    return 0.5f * x * (1.0f + erff(x * 0.70710678118654752f));
}
__device__ __forceinline__ unsigned bf16_rne(float x) {
    unsigned u = __float_as_uint(x);
    return (u + 0x7FFFu + ((u >> 16) & 1u)) >> 16;
}
__device__ __forceinline__ unsigned pack2(float lo, float hi) {
    return (bf16_rne(hi) << 16) | bf16_rne(lo);
}

// ---------------------------------------------------------------------------
// Fused kernel: one wave per row, 4 waves/block.
//  1. block stages W2 as bf16 into LDS (XOR-swizzled 16B slots) + b2
//  2. each wave streams its row's 2048 anchors -> per-lane sorted top-8
//     -> wave merge (8x argmin-pop) -> softmax weights
//  3. layer1: lane computes h1[k][2*lane..2*lane+1] (exact-erf GELU),
//     writes bf16 pairs to swizzled LDS tile
//  4. layer2 via mfma_f32_16x16x32_bf16: A = W2 (M=f), B = h1^T (N=k-slot);
//     D col = lane&15 = k-slot, D row = f. Columns 8..15 are garbage and
//     are discarded (each D column is an independent dot product).
//  5. epilogue: gelu(acc+b2)*w[k], reduce over k via 3x shfl_xor, float4 store
// ---------------------------------------------------------------------------
__global__ void __launch_bounds__(256, 3) fused_anchor_mlp(
    const float* __restrict__ Gl, const float* __restrict__ ancL,
    const float* __restrict__ W1, const float* __restrict__ b1,
    const float* __restrict__ W2, const float* __restrict__ b2,
    float* __restrict__ out)
{
    __shared__ uint4  w2s[2048];    // 128 rows x 16 slots (bf16x8), 32 KB
    __shared__ uint4  h1s4[1024];   // 4 waves x 16 rows x 16 slots, 16 KB
    __shared__ float4 b2s4[32];     // 512 B

    const int tid  = threadIdx.x;
    const int wave = tid >> 6;
    const int lane = tid & 63;
    const int row  = (blockIdx.x << 2) + wave;

    // --- stage W2 (f32 -> bf16, swizzle: phys_slot = slot ^ (row&7)) ---
    {
        const float4* w2f = reinterpret_cast<const float4*>(W2);
        for (int i = tid; i < 2048; i += 256) {
            const float4 lo = w2f[i * 2], hi = w2f[i * 2 + 1];
            uint4 u;
            u.x = pack2(lo.x, lo.y); u.y = pack2(lo.z, lo.w);
            u.z = pack2(hi.x, hi.y); u.w = pack2(hi.z, hi.w);
            w2s[(i & ~15) | ((i & 15) ^ ((i >> 4) & 7))] = u;
        }
        if (tid < 32) b2s4[tid] = reinterpret_cast<const float4*>(b2)[tid];
    }
    // (single __syncthreads below, after h1 writes, covers this staging too)

    // --- phase 1: stream anchors, per-lane sorted top-8 ---
    const float2 g = reinterpret_cast<const float2*>(Gl)[row];
    const float4* a4 = reinterpret_cast<const float4*>(ancL) + (size_t)row * (NM / 2);

    float bd[8], bax[8], bay[8];
#pragma unroll
    for (int i = 0; i < 8; ++i) { bd[i] = FLT_BIG; bax[i] = 0.f; bay[i] = 0.f; }

#pragma unroll 4
    for (int it = 0; it < NM / 128; ++it) {
        float4 v = a4[it * 64 + lane];
#pragma unroll
        for (int h = 0; h < 2; ++h) {
            const float ax = h ? v.z : v.x;
            const float ay = h ? v.w : v.y;
            const float dx = ax - g.x, dy = ay - g.y;
            // bit-identical to numpy: no fma contraction
            const float d = __fadd_rn(__fmul_rn(dx, dx), __fmul_rn(dy, dy));
            if (d < bd[7]) {
#pragma unroll
                for (int j = 7; j >= 1; --j) {
                    const bool c1 = bd[j - 1] > d;
                    const bool c2 = bd[j] > d;
                    const float nd = c1 ? bd[j - 1] : (c2 ? d : bd[j]);
                    const float nx = c1 ? bax[j - 1] : (c2 ? ax : bax[j]);
                    const float ny = c1 ? bay[j - 1] : (c2 ? ay : bay[j]);
                    bd[j] = nd; bax[j] = nx; bay[j] = ny;
                }
                if (bd[0] > d) { bd[0] = d; bax[0] = ax; bay[0] = ay; }
            }
        }
    }

    // --- wave merge: 8x (argmin over 64 lane-heads, pop winner) ---
    float td[8], tax[8], tay[8];
#pragma unroll
    for (int k = 0; k < 8; ++k) {
        float d = bd[0];
        int   src = lane;
#pragma unroll
        for (int off = 32; off >= 1; off >>= 1) {
            const float od = __shfl_xor(d, off);
            const int   os = __shfl_xor(src, off);
            if (od < d || (od == d && os < src)) { d = od; src = os; }
        }
        td[k]  = d;
        tax[k] = __shfl(bax[0], src);
        tay[k] = __shfl(bay[0], src);
        if (lane == src) {
#pragma unroll
            for (int j = 0; j < 7; ++j) { bd[j] = bd[j + 1]; bax[j] = bax[j + 1]; bay[j] = bay[j + 1]; }
            bd[7] = FLT_BIG;
        }
    }

    // --- softmax(d2/tau); per-lane weight select (k-slot = lane&15) ---
    const float mx = td[7];
    float ek[8], ssum = 0.f;
#pragma unroll
    for (int k = 0; k < 8; ++k) { ek[k] = expf((td[k] - mx) * (1.0f / TAU)); ssum += ek[k]; }
    const float inv = 1.0f / ssum;
    float wsel = 0.f;
#pragma unroll
    for (int k = 0; k < 8; ++k) wsel = ((lane & 15) == k) ? ek[k] * inv : wsel;

    // --- layer 1: lane owns e0=2*lane, e1=2*lane+1; write bf16 pairs ---
    const float4 w1v = reinterpret_cast<const float4*>(W1)[lane];  // W1[e0][0..1], W1[e1][0..1]
    const float2 b1v = reinterpret_cast<const float2*>(b1)[lane];
    unsigned* h1w = reinterpret_cast<unsigned*>(h1s4 + (wave << 8));
#pragma unroll
    for (int k = 0; k < 8; ++k) {
        const float x0 = fmaf(tax[k], w1v.x, fmaf(tay[k], w1v.y, b1v.x));
        const float x1 = fmaf(tax[k], w1v.z, fmaf(tay[k], w1v.w, b1v.y));
        // row k (256B = 64 words), slot = lane>>2 swizzled by k, word = lane&3
        h1w[(k << 6) + ((((lane >> 2) ^ k) << 2) | (lane & 3))] = pack2(gelu_exact(x0), gelu_exact(x1));
    }
    __syncthreads();

    // --- B fragments (h1^T): lane holds B[ks*32+(l>>4)*8+j][l&15] ---
    const uint4* h1b = h1s4 + (wave << 8);
    const int bslot = lane >> 4, bxor = lane & 7, brow = (lane & 15) * 16;
    bf16x8 bq0 = __builtin_bit_cast(bf16x8, h1b[brow + (( 0 + bslot) ^ bxor)]);
    bf16x8 bq1 = __builtin_bit_cast(bf16x8, h1b[brow + (( 4 + bslot) ^ bxor)]);
    bf16x8 bq2 = __builtin_bit_cast(bf16x8, h1b[brow + (( 8 + bslot) ^ bxor)]);
    bf16x8 bq3 = __builtin_bit_cast(bf16x8, h1b[brow + ((12 + bslot) ^ bxor)]);

    // --- MFMA over 8 f-tiles + fused epilogue ---
    const size_t outbase = (size_t)row * NEMB;
#pragma unroll 2
    for (int ft = 0; ft < 8; ++ft) {
        const int arow = (ft * 16 + (lane & 15)) * 16;
        f32x4 acc = {0.f, 0.f, 0.f, 0.f};
        acc = __builtin_amdgcn_mfma_f32_16x16x32_bf16(
                  __builtin_bit_cast(bf16x8, w2s[arow + (( 0 + bslot) ^ bxor)]), bq0, acc, 0, 0, 0);
        acc = __builtin_amdgcn_mfma_f32_16x16x32_bf16(
                  __builtin_bit_cast(bf16x8, w2s[arow + (( 4 + bslot) ^ bxor)]), bq1, acc, 0, 0, 0);
        acc = __builtin_amdgcn_mfma_f32_16x16x32_bf16(
                  __builtin_bit_cast(bf16x8, w2s[arow + (( 8 + bslot) ^ bxor)]), bq2, acc, 0, 0, 0);
        acc = __builtin_amdgcn_mfma_f32_16x16x32_bf16(
                  __builtin_bit_cast(bf16x8, w2s[arow + ((12 + bslot) ^ bxor)]), bq3, acc, 0, 0, 0);

        // D: row f = ft*16 + (lane>>4)*4 + reg, col k-slot = lane&15
        const float4 b2v = b2s4[ft * 4 + (lane >> 4)];
        float s0 = gelu_exact(acc[0] + b2v.x) * wsel;
        float s1 = gelu_exact(acc[1] + b2v.y) * wsel;
        float s2 = gelu_exact(acc[2] + b2v.z) * wsel;
        float s3 = gelu_exact(acc[3] + b2v.w) * wsel;
        // weighted sum over k = reduce over lanes xor 1,2,4 (stays within k-slots 0..7)
        s0 += __shfl_xor(s0, 1); s0 += __shfl_xor(s0, 2); s0 += __shfl_xor(s0, 4);
        s1 += __shfl_xor(s1, 1); s1 += __shfl_xor(s1, 2); s1 += __shfl_xor(s1, 4);
        s2 += __shfl_xor(s2, 1); s2 += __shfl_xor(s2, 2); s2 += __shfl_xor(s2, 4);
        s3 += __shfl_xor(s3, 1); s3 += __shfl_xor(s3, 2); s3 += __shfl_xor(s3, 4);
        if ((lane & 15) == 0)
            *reinterpret_cast<float4*>(&out[outbase + ft * 16 + ((lane >> 4) << 2)]) =
                make_float4(s0, s1, s2, s3);
    }
}

extern "C" void kernel_launch(void* const* d_in, const int* in_sizes, int n_in,
                              void* d_out, int out_size, void* d_ws, size_t ws_size,
                              hipStream_t stream)
{
    const float* Gl  = (const float*)d_in[0];
    const float* anc = (const float*)d_in[1];
    const float* W1  = (const float*)d_in[2];
    const float* b1  = (const float*)d_in[3];
    const float* W2  = (const float*)d_in[4];
    const float* b2  = (const float*)d_in[5];
    float* outp = (float*)d_out;

    fused_anchor_mlp<<<NB / 4, 256, 0, stream>>>(Gl, anc, W1, b1, W2, b2, outp);
}

// Round 3
// 178.878 us; speedup vs baseline: 2.2433x; 2.2433x over previous
//
#include <hip/hip_runtime.h>
#include <math.h>

#define NB   32768
#define NM   2048
#define NEMB 128
#define NK   8
#define TAU  0.3f
#define FLT_BIG 3.402823466e38f

typedef __attribute__((ext_vector_type(8))) short bf16x8;
typedef __attribute__((ext_vector_type(4))) float f32x4;

__device__ __forceinline__ float gelu_exact(float x) {
    return 0.5f * x * (1.0f + erff(x * 0.70710678118654752f));
}
__device__ __forceinline__ unsigned bf16_rne(float x) {
    unsigned u = __float_as_uint(x);
    return (u + 0x7FFFu + ((u >> 16) & 1u)) >> 16;
}
__device__ __forceinline__ unsigned pack2(float lo, float hi) {
    return (bf16_rne(hi) << 16) | bf16_rne(lo);
}

// ---------------------------------------------------------------------------
// Fused kernel, 512 threads = 8 waves, one row per wave.
// Phase 1: per-lane SORTED TOP-4 (cheap 21-op insert, shallow dep chain)
//          -> 8x wave-argmin-pop extraction -> exactness fallback (rare,
//          P~3e-4/row) re-runs a full per-lane top-8 scan when any lane
//          had all 4 of its kept candidates extracted.
// Phase 2: softmax weights + layer1 GELU -> bf16 h1 tile (8 k-rows, LDS,
//          XOR-swizzled) -> mfma_f32_16x16x32_bf16 with A=W2 (bf16, LDS,
//          swizzled, staged once per block) -> fused gelu/weighted-combine.
// LDS 49.7 KB, __launch_bounds__(512,6) -> 3 blocks/CU = 24 waves/CU.
// ---------------------------------------------------------------------------
__global__ void __launch_bounds__(512, 6) fused_anchor_mlp(
    const float* __restrict__ Gl, const float* __restrict__ ancL,
    const float* __restrict__ W1, const float* __restrict__ b1,
    const float* __restrict__ W2, const float* __restrict__ b2,
    float* __restrict__ out)
{
    __shared__ uint4  w2s[2048];      // 128 rows x 16 slots bf16x8, 32 KB
    __shared__ uint4  h1s4[8 * 128];  // 8 waves x 8 k-rows x 16 slots, 16 KB
    __shared__ float4 b2s4[32];       // 512 B

    const int tid  = threadIdx.x;
    const int wave = tid >> 6;
    const int lane = tid & 63;
    const int row  = (blockIdx.x << 3) + wave;

    // --- stage W2 (f32 -> bf16, phys_slot = slot ^ (row&7)) ---
    {
        const float4* w2f = reinterpret_cast<const float4*>(W2);
        for (int i = tid; i < 2048; i += 512) {
            const float4 lo = w2f[i * 2], hi = w2f[i * 2 + 1];
            uint4 u;
            u.x = pack2(lo.x, lo.y); u.y = pack2(lo.z, lo.w);
            u.z = pack2(hi.x, hi.y); u.w = pack2(hi.z, hi.w);
            w2s[(i & ~15) | ((i & 15) ^ ((i >> 4) & 7))] = u;
        }
        if (tid < 32) b2s4[tid] = reinterpret_cast<const float4*>(b2)[tid];
    }
    // single __syncthreads below (after h1 writes) covers this staging

    // --- phase 1: stream anchors, per-lane sorted top-4 ---
    const float2 g = reinterpret_cast<const float2*>(Gl)[row];
    const float4* a4 = reinterpret_cast<const float4*>(ancL) + (size_t)row * (NM / 2);

    float bd[4], bax[4], bay[4];
#pragma unroll
    for (int i = 0; i < 4; ++i) { bd[i] = FLT_BIG; bax[i] = 0.f; bay[i] = 0.f; }

    auto ins4 = [&](float d, float x, float y) {
        // precondition: d < bd[3]; all cmps on OLD values
        const bool c0 = bd[0] > d, c1 = bd[1] > d, c2 = bd[2] > d;
        bd[3]  = c2 ? bd[2]  : d;
        bax[3] = c2 ? bax[2] : x;
        bay[3] = c2 ? bay[2] : y;
        bd[2]  = c1 ? bd[1]  : (c2 ? d : bd[2]);
        bax[2] = c1 ? bax[1] : (c2 ? x : bax[2]);
        bay[2] = c1 ? bay[1] : (c2 ? y : bay[2]);
        bd[1]  = c0 ? bd[0]  : (c1 ? d : bd[1]);
        bax[1] = c0 ? bax[0] : (c1 ? x : bax[1]);
        bay[1] = c0 ? bay[0] : (c1 ? y : bay[1]);
        if (c0) { bd[0] = d; bax[0] = x; bay[0] = y; }
    };

    float4 v = a4[lane];
#pragma unroll 4
    for (int it = 0; it < 16; ++it) {
        float4 vn;
        if (it < 15) vn = a4[(it + 1) * 64 + lane];
        const float dx0 = v.x - g.x, dy0 = v.y - g.y;
        const float dx1 = v.z - g.x, dy1 = v.w - g.y;
        // bit-identical to numpy: no fma contraction
        const float d0 = __fadd_rn(__fmul_rn(dx0, dx0), __fmul_rn(dy0, dy0));
        const float d1 = __fadd_rn(__fmul_rn(dx1, dx1), __fmul_rn(dy1, dy1));
        if (fminf(d0, d1) < bd[3]) {
            if (d0 < bd[3]) ins4(d0, v.x, v.y);
            if (d1 < bd[3]) ins4(d1, v.z, v.w);
        }
        if (it < 15) v = vn;
    }

    // --- extraction: 8x (wave argmin over lane heads, pop winner) ---
    float td[8], tax[8], tay[8];
    int pops = 0;
#pragma unroll
    for (int k = 0; k < 8; ++k) {
        float d = bd[0];
        int   src = lane;
#pragma unroll
        for (int off = 32; off >= 1; off >>= 1) {
            const float od = __shfl_xor(d, off);
            const int   os = __shfl_xor(src, off);
            if (od < d || (od == d && os < src)) { d = od; src = os; }
        }
        td[k]  = d;
        tax[k] = __shfl(bax[0], src);
        tay[k] = __shfl(bay[0], src);
        if (lane == src) {
            ++pops;
            bd[0] = bd[1]; bax[0] = bax[1]; bay[0] = bay[1];
            bd[1] = bd[2]; bax[1] = bax[2]; bay[1] = bay[2];
            bd[2] = bd[3]; bax[2] = bax[3]; bay[2] = bay[3];
            bd[3] = FLT_BIG;
        }
    }

    // --- exactness fallback: a lane contributed all 4 kept -> its 5th-best
    //     might belong in the top-8. Re-run full per-lane top-8 scan. Rare. ---
    if (__ballot(pops == 4)) {
        float fd[8], fx[8], fy[8];
#pragma unroll
        for (int i = 0; i < 8; ++i) { fd[i] = FLT_BIG; fx[i] = 0.f; fy[i] = 0.f; }
        for (int it = 0; it < 16; ++it) {
            const float4 vv = a4[it * 64 + lane];
#pragma unroll
            for (int h = 0; h < 2; ++h) {
                const float ax = h ? vv.z : vv.x;
                const float ay = h ? vv.w : vv.y;
                const float ddx = ax - g.x, ddy = ay - g.y;
                const float d = __fadd_rn(__fmul_rn(ddx, ddx), __fmul_rn(ddy, ddy));
                if (d < fd[7]) {
#pragma unroll
                    for (int j = 7; j >= 1; --j) {
                        const bool s1 = fd[j - 1] > d;
                        const bool s2 = fd[j] > d;
                        const float nd = s1 ? fd[j - 1] : (s2 ? d : fd[j]);
                        const float nx = s1 ? fx[j - 1] : (s2 ? ax : fx[j]);
                        const float ny = s1 ? fy[j - 1] : (s2 ? ay : fy[j]);
                        fd[j] = nd; fx[j] = nx; fy[j] = ny;
                    }
                    if (fd[0] > d) { fd[0] = d; fx[0] = ax; fy[0] = ay; }
                }
            }
        }
#pragma unroll
        for (int k = 0; k < 8; ++k) {
            float d = fd[0];
            int   src = lane;
#pragma unroll
            for (int off = 32; off >= 1; off >>= 1) {
                const float od = __shfl_xor(d, off);
                const int   os = __shfl_xor(src, off);
                if (od < d || (od == d && os < src)) { d = od; src = os; }
            }
            td[k]  = d;
            tax[k] = __shfl(fx[0], src);
            tay[k] = __shfl(fy[0], src);
            if (lane == src) {
#pragma unroll
                for (int j = 0; j < 7; ++j) { fd[j] = fd[j + 1]; fx[j] = fx[j + 1]; fy[j] = fy[j + 1]; }
                fd[7] = FLT_BIG;
            }
        }
    }

    // --- softmax(d2/tau); per-lane weight (k-slot = lane&15, 0 for >=8) ---
    const float mx = td[7];
    float ek[8], ssum = 0.f;
#pragma unroll
    for (int k = 0; k < 8; ++k) { ek[k] = expf((td[k] - mx) * (1.0f / TAU)); ssum += ek[k]; }
    const float inv = 1.0f / ssum;
    float wsel = 0.f;
#pragma unroll
    for (int k = 0; k < 8; ++k) wsel = ((lane & 15) == k) ? ek[k] * inv : wsel;

    // --- layer 1: lane owns e0=2*lane, e1=2*lane+1; bf16 pairs to LDS ---
    const float4 w1v = reinterpret_cast<const float4*>(W1)[lane];
    const float2 b1v = reinterpret_cast<const float2*>(b1)[lane];
    unsigned* h1w = reinterpret_cast<unsigned*>(h1s4 + (wave << 7));
#pragma unroll
    for (int k = 0; k < 8; ++k) {
        const float x0 = fmaf(tax[k], w1v.x, fmaf(tay[k], w1v.y, b1v.x));
        const float x1 = fmaf(tax[k], w1v.z, fmaf(tay[k], w1v.w, b1v.y));
        // row k, phys slot = (lane>>2)^k, word = lane&3
        h1w[(k << 6) + ((((lane >> 2) ^ k) << 2) | (lane & 3))] = pack2(gelu_exact(x0), gelu_exact(x1));
    }
    __syncthreads();

    // --- B fragments (h1^T): row r = lane&7 (cols 8..15 duplicate 0..7) ---
    const uint4* h1b = h1s4 + (wave << 7);
    const int bslot = lane >> 4, bxor = lane & 7, brow = (lane & 7) * 16;
    bf16x8 bq0 = __builtin_bit_cast(bf16x8, h1b[brow + (( 0 + bslot) ^ bxor)]);
    bf16x8 bq1 = __builtin_bit_cast(bf16x8, h1b[brow + (( 4 + bslot) ^ bxor)]);
    bf16x8 bq2 = __builtin_bit_cast(bf16x8, h1b[brow + (( 8 + bslot) ^ bxor)]);
    bf16x8 bq3 = __builtin_bit_cast(bf16x8, h1b[brow + ((12 + bslot) ^ bxor)]);

    // --- MFMA over 8 f-tiles + fused epilogue ---
    const size_t outbase = (size_t)row * NEMB;
#pragma unroll 2
    for (int ft = 0; ft < 8; ++ft) {
        const int arow = (ft * 16 + (lane & 15)) * 16;
        f32x4 acc = {0.f, 0.f, 0.f, 0.f};
        acc = __builtin_amdgcn_mfma_f32_16x16x32_bf16(
                  __builtin_bit_cast(bf16x8, w2s[arow + (( 0 + bslot) ^ bxor)]), bq0, acc, 0, 0, 0);
        acc = __builtin_amdgcn_mfma_f32_16x16x32_bf16(
                  __builtin_bit_cast(bf16x8, w2s[arow + (( 4 + bslot) ^ bxor)]), bq1, acc, 0, 0, 0);
        acc = __builtin_amdgcn_mfma_f32_16x16x32_bf16(
                  __builtin_bit_cast(bf16x8, w2s[arow + (( 8 + bslot) ^ bxor)]), bq2, acc, 0, 0, 0);
        acc = __builtin_amdgcn_mfma_f32_16x16x32_bf16(
                  __builtin_bit_cast(bf16x8, w2s[arow + ((12 + bslot) ^ bxor)]), bq3, acc, 0, 0, 0);

        // D: row f = ft*16 + (lane>>4)*4 + reg, col k-slot = lane&15
        const float4 b2v = b2s4[ft * 4 + (lane >> 4)];
        float s0 = gelu_exact(acc[0] + b2v.x) * wsel;
        float s1 = gelu_exact(acc[1] + b2v.y) * wsel;
        float s2 = gelu_exact(acc[2] + b2v.z) * wsel;
        float s3 = gelu_exact(acc[3] + b2v.w) * wsel;
        s0 += __shfl_xor(s0, 1); s0 += __shfl_xor(s0, 2); s0 += __shfl_xor(s0, 4);
        s1 += __shfl_xor(s1, 1); s1 += __shfl_xor(s1, 2); s1 += __shfl_xor(s1, 4);
        s2 += __shfl_xor(s2, 1); s2 += __shfl_xor(s2, 2); s2 += __shfl_xor(s2, 4);
        s3 += __shfl_xor(s3, 1); s3 += __shfl_xor(s3, 2); s3 += __shfl_xor(s3, 4);
        if ((lane & 15) == 0)
            *reinterpret_cast<float4*>(&out[outbase + ft * 16 + ((lane >> 4) << 2)]) =
                make_float4(s0, s1, s2, s3);
    }
}

extern "C" void kernel_launch(void* const* d_in, const int* in_sizes, int n_in,
                              void* d_out, int out_size, void* d_ws, size_t ws_size,
                              hipStream_t stream)
{
    const float* Gl  = (const float*)d_in[0];
    const float* anc = (const float*)d_in[1];
    const float* W1  = (const float*)d_in[2];
    const float* b1  = (const float*)d_in[3];
    const float* W2  = (const float*)d_in[4];
    const float* b2  = (const float*)d_in[5];
    float* outp = (float*)d_out;

    fused_anchor_mlp<<<NB / 8, 512, 0, stream>>>(Gl, anc, W1, b1, W2, b2, outp);
}

// Round 5
// 148.130 us; speedup vs baseline: 2.7089x; 1.2076x over previous
//
#include <hip/hip_runtime.h>
#include <hip/hip_bf16.h>
#include <math.h>

#define NB   32768
#define NM   2048
#define NEMB 128
#define NK   8
#define TAU  0.3f
#define FLT_BIG 3.402823466e38f

typedef __attribute__((ext_vector_type(8))) short bf16x8;
typedef __attribute__((ext_vector_type(4))) float f32x4;

// fast exact-erf GELU: Abramowitz-Stegun 7.1.26, |erf err| <= 1.5e-7,
// single path (no divergence), v_rcp + v_exp
__device__ __forceinline__ float gelu_fast(float x) {
    const float z = fabsf(x) * 0.70710678118654752f;
    const float t = __builtin_amdgcn_rcpf(fmaf(0.3275911f, z, 1.0f));
    float p = fmaf(1.061405429f, t, -1.453152027f);
    p = fmaf(p, t, 1.421413741f);
    p = fmaf(p, t, -0.284496736f);
    p = fmaf(p, t, 0.254829592f);
    p = p * t;
    const float e = __expf(-z * z);
    const float erfa = fmaf(-p, e, 1.0f);
    const float s = (x >= 0.0f) ? erfa : -erfa;
    const float hx = 0.5f * x;
    return fmaf(hx, s, hx);
}
// f32 pair -> packed bf16 (RNE) via v_cvt_pk_bf16_f32
__device__ __forceinline__ unsigned pack2(float lo, float hi) {
    __hip_bfloat162 b = __float22bfloat162_rn(make_float2(lo, hi));
    return *reinterpret_cast<unsigned*>(&b);
}

// ---------------------------------------------------------------------------
// Fused kernel, 512 threads = 8 waves = 8 rows/block.
// Phase 1 (per wave): stream 2048 anchors (nontemporal float4), per-lane
//   sorted top-4, 8x wave-argmin-pop, exactness fallback (P~3e-4/row).
// Phase 2: waves pair up (2 rows per MFMA pass): B cols 0..7 = row-even k,
//   cols 8..15 = row-odd k. Wave half h does f-tiles h*4..h*4+3 for BOTH
//   rows -> no garbage lanes in epilogue, MFMA count halved.
// ---------------------------------------------------------------------------
__global__ void __launch_bounds__(512, 6) fused_anchor_mlp(
    const float* __restrict__ Gl, const float* __restrict__ ancL,
    const float* __restrict__ W1, const float* __restrict__ b1,
    const float* __restrict__ W2, const float* __restrict__ b2,
    float* __restrict__ out)
{
    __shared__ uint4  w2s[2048];      // 128 rows x 16 slots bf16x8, 32 KB
    __shared__ uint4  h1s4[1024];     // 4 pairs x 16 k-rows x 16 slots, 16 KB
    __shared__ float4 b2s4[32];       // 512 B
    __shared__ float  wts[8][8];      // softmax weights per row, 256 B

    const int tid  = threadIdx.x;
    const int wave = tid >> 6;
    const int lane = tid & 63;
    const int pair = wave >> 1;
    const int half = wave & 1;
    const int rowbase = blockIdx.x << 3;
    const int row  = rowbase + wave;

    // --- stage W2 (f32 -> bf16, phys_slot = slot ^ (row&7)) ---
    {
        const float4* w2f = reinterpret_cast<const float4*>(W2);
        for (int i = tid; i < 2048; i += 512) {
            const float4 lo = w2f[i * 2], hi = w2f[i * 2 + 1];
            uint4 u;
            u.x = pack2(lo.x, lo.y); u.y = pack2(lo.z, lo.w);
            u.z = pack2(hi.x, hi.y); u.w = pack2(hi.z, hi.w);
            w2s[(i & ~15) | ((i & 15) ^ ((i >> 4) & 7))] = u;
        }
        if (tid < 32) b2s4[tid] = reinterpret_cast<const float4*>(b2)[tid];
    }
    // single __syncthreads below (after h1 writes) covers all staging

    // --- phase 1: stream anchors, per-lane sorted top-4 ---
    const float2 g = reinterpret_cast<const float2*>(Gl)[row];
    const f32x4* a4 = reinterpret_cast<const f32x4*>(ancL) + (size_t)row * (NM / 2);

    float bd[4], bax[4], bay[4];
#pragma unroll
    for (int i = 0; i < 4; ++i) { bd[i] = FLT_BIG; bax[i] = 0.f; bay[i] = 0.f; }

    auto ins4 = [&](float d, float x, float y) {
        const bool c0 = bd[0] > d, c1 = bd[1] > d, c2 = bd[2] > d;
        bd[3]  = c2 ? bd[2]  : d;
        bax[3] = c2 ? bax[2] : x;
        bay[3] = c2 ? bay[2] : y;
        bd[2]  = c1 ? bd[1]  : (c2 ? d : bd[2]);
        bax[2] = c1 ? bax[1] : (c2 ? x : bax[2]);
        bay[2] = c1 ? bay[1] : (c2 ? y : bay[2]);
        bd[1]  = c0 ? bd[0]  : (c1 ? d : bd[1]);
        bax[1] = c0 ? bax[0] : (c1 ? x : bax[1]);
        bay[1] = c0 ? bay[0] : (c1 ? y : bay[1]);
        if (c0) { bd[0] = d; bax[0] = x; bay[0] = y; }
    };

    f32x4 v = __builtin_nontemporal_load(&a4[lane]);
#pragma unroll 4
    for (int it = 0; it < 16; ++it) {
        f32x4 vn;
        if (it < 15) vn = __builtin_nontemporal_load(&a4[(it + 1) * 64 + lane]);
        const float dx0 = v.x - g.x, dy0 = v.y - g.y;
        const float dx1 = v.z - g.x, dy1 = v.w - g.y;
        // bit-identical to numpy: no fma contraction
        const float d0 = __fadd_rn(__fmul_rn(dx0, dx0), __fmul_rn(dy0, dy0));
        const float d1 = __fadd_rn(__fmul_rn(dx1, dx1), __fmul_rn(dy1, dy1));
        if (fminf(d0, d1) < bd[3]) {
            if (d0 < bd[3]) ins4(d0, v.x, v.y);
            if (d1 < bd[3]) ins4(d1, v.z, v.w);
        }
        if (it < 15) v = vn;
    }

    // --- extraction: 8x (wave argmin over lane heads, pop winner) ---
    float td[8], tax[8], tay[8];
    int pops = 0;
#pragma unroll
    for (int k = 0; k < 8; ++k) {
        float d = bd[0];
        int   src = lane;
#pragma unroll
        for (int off = 32; off >= 1; off >>= 1) {
            const float od = __shfl_xor(d, off);
            const int   os = __shfl_xor(src, off);
            if (od < d || (od == d && os < src)) { d = od; src = os; }
        }
        td[k]  = d;
        tax[k] = __shfl(bax[0], src);
        tay[k] = __shfl(bay[0], src);
        if (lane == src) {
            ++pops;
            bd[0] = bd[1]; bax[0] = bax[1]; bay[0] = bay[1];
            bd[1] = bd[2]; bax[1] = bax[2]; bay[1] = bay[2];
            bd[2] = bd[3]; bax[2] = bax[3]; bay[2] = bay[3];
            bd[3] = FLT_BIG;
        }
    }

    // --- exactness fallback (rare): some lane had all 4 kept extracted ---
    if (__ballot(pops == 4)) {
        float fd[8], fx[8], fy[8];
#pragma unroll
        for (int i = 0; i < 8; ++i) { fd[i] = FLT_BIG; fx[i] = 0.f; fy[i] = 0.f; }
        for (int it = 0; it < 16; ++it) {
            const f32x4 vv = a4[it * 64 + lane];
#pragma unroll
            for (int h = 0; h < 2; ++h) {
                const float ax = h ? vv.z : vv.x;
                const float ay = h ? vv.w : vv.y;
                const float ddx = ax - g.x, ddy = ay - g.y;
                const float d = __fadd_rn(__fmul_rn(ddx, ddx), __fmul_rn(ddy, ddy));
                if (d < fd[7]) {
#pragma unroll
                    for (int j = 7; j >= 1; --j) {
                        const bool s1 = fd[j - 1] > d;
                        const bool s2 = fd[j] > d;
                        const float nd = s1 ? fd[j - 1] : (s2 ? d : fd[j]);
                        const float nx = s1 ? fx[j - 1] : (s2 ? ax : fx[j]);
                        const float ny = s1 ? fy[j - 1] : (s2 ? ay : fy[j]);
                        fd[j] = nd; fx[j] = nx; fy[j] = ny;
                    }
                    if (fd[0] > d) { fd[0] = d; fx[0] = ax; fy[0] = ay; }
                }
            }
        }
#pragma unroll
        for (int k = 0; k < 8; ++k) {
            float d = fd[0];
            int   src = lane;
#pragma unroll
            for (int off = 32; off >= 1; off >>= 1) {
                const float od = __shfl_xor(d, off);
                const int   os = __shfl_xor(src, off);
                if (od < d || (od == d && os < src)) { d = od; src = os; }
            }
            td[k]  = d;
            tax[k] = __shfl(fx[0], src);
            tay[k] = __shfl(fy[0], src);
            if (lane == src) {
#pragma unroll
                for (int j = 0; j < 7; ++j) { fd[j] = fd[j + 1]; fx[j] = fx[j + 1]; fy[j] = fy[j + 1]; }
                fd[7] = FLT_BIG;
            }
        }
    }

    // --- softmax(d2/tau); publish weights for the pair epilogue ---
    const float mx = td[7];
    float ek[8], ssum = 0.f;
#pragma unroll
    for (int k = 0; k < 8; ++k) { ek[k] = __expf((td[k] - mx) * (1.0f / TAU)); ssum += ek[k]; }
    const float inv = 1.0f / ssum;
    float wv = 0.f;
#pragma unroll
    for (int k = 0; k < 8; ++k) wv = (lane == k) ? ek[k] * inv : wv;
    if (lane < 8) wts[wave][lane] = wv;

    // --- layer 1: lane owns e0=2*lane, e1=2*lane+1; write to pair tile ---
    const float4 w1v = reinterpret_cast<const float4*>(W1)[lane];
    const float2 b1v = reinterpret_cast<const float2*>(b1)[lane];
    unsigned* h1w = reinterpret_cast<unsigned*>(h1s4 + (pair << 8));
#pragma unroll
    for (int k = 0; k < 8; ++k) {
        const float x0 = fmaf(tax[k], w1v.x, fmaf(tay[k], w1v.y, b1v.x));
        const float x1 = fmaf(tax[k], w1v.z, fmaf(tay[k], w1v.w, b1v.y));
        const int r = (half << 3) + k;   // row in pair tile; swizzle key k = r&7
        h1w[(r << 6) + ((((lane >> 2) ^ k) << 2) | (lane & 3))] = pack2(gelu_fast(x0), gelu_fast(x1));
    }
    __syncthreads();

    // --- B fragments from pair tile: col n = lane&15 (0..7 even, 8..15 odd) ---
    const uint4* h1b = h1s4 + (pair << 8);
    const int bslot = lane >> 4, bxor = lane & 7, brow = (lane & 15) * 16;
    bf16x8 bq0 = __builtin_bit_cast(bf16x8, h1b[brow + (( 0 + bslot) ^ bxor)]);
    bf16x8 bq1 = __builtin_bit_cast(bf16x8, h1b[brow + (( 4 + bslot) ^ bxor)]);
    bf16x8 bq2 = __builtin_bit_cast(bf16x8, h1b[brow + (( 8 + bslot) ^ bxor)]);
    bf16x8 bq3 = __builtin_bit_cast(bf16x8, h1b[brow + ((12 + bslot) ^ bxor)]);

    // weight for this lane's D column
    const float wsel = wts[(pair << 1) | ((lane >> 3) & 1)][lane & 7];

    // --- MFMA: this wave does f-tiles half*4 .. half*4+3 for BOTH rows ---
#pragma unroll 2
    for (int i = 0; i < 4; ++i) {
        const int ft = (half << 2) + i;
        const int arow = (ft * 16 + (lane & 15)) * 16;
        f32x4 acc = {0.f, 0.f, 0.f, 0.f};
        acc = __builtin_amdgcn_mfma_f32_16x16x32_bf16(
                  __builtin_bit_cast(bf16x8, w2s[arow + (( 0 + bslot) ^ bxor)]), bq0, acc, 0, 0, 0);
        acc = __builtin_amdgcn_mfma_f32_16x16x32_bf16(
                  __builtin_bit_cast(bf16x8, w2s[arow + (( 4 + bslot) ^ bxor)]), bq1, acc, 0, 0, 0);
        acc = __builtin_amdgcn_mfma_f32_16x16x32_bf16(
                  __builtin_bit_cast(bf16x8, w2s[arow + (( 8 + bslot) ^ bxor)]), bq2, acc, 0, 0, 0);
        acc = __builtin_amdgcn_mfma_f32_16x16x32_bf16(
                  __builtin_bit_cast(bf16x8, w2s[arow + ((12 + bslot) ^ bxor)]), bq3, acc, 0, 0, 0);

        // D: row f = ft*16 + (lane>>4)*4 + j, col = lane&15
        const float4 b2v = b2s4[ft * 4 + (lane >> 4)];
        float s0 = gelu_fast(acc[0] + b2v.x) * wsel;
        float s1 = gelu_fast(acc[1] + b2v.y) * wsel;
        float s2 = gelu_fast(acc[2] + b2v.z) * wsel;
        float s3 = gelu_fast(acc[3] + b2v.w) * wsel;
        // reduce over k within each 8-col group (xor 1,2,4 keeps bit3)
        s0 += __shfl_xor(s0, 1); s0 += __shfl_xor(s0, 2); s0 += __shfl_xor(s0, 4);
        s1 += __shfl_xor(s1, 1); s1 += __shfl_xor(s1, 2); s1 += __shfl_xor(s1, 4);
        s2 += __shfl_xor(s2, 1); s2 += __shfl_xor(s2, 2); s2 += __shfl_xor(s2, 4);
        s3 += __shfl_xor(s3, 1); s3 += __shfl_xor(s3, 2); s3 += __shfl_xor(s3, 4);
        if ((lane & 7) == 0) {
            const int which = (lane >> 3) & 1;   // 0 = row even, 1 = row odd
            const size_t ob = (size_t)(rowbase + (pair << 1) + which) * NEMB
                              + ft * 16 + ((lane >> 4) << 2);
            *reinterpret_cast<float4*>(&out[ob]) = make_float4(s0, s1, s2, s3);
        }
    }
}

extern "C" void kernel_launch(void* const* d_in, const int* in_sizes, int n_in,
                              void* d_out, int out_size, void* d_ws, size_t ws_size,
                              hipStream_t stream)
{
    const float* Gl  = (const float*)d_in[0];
    const float* anc = (const float*)d_in[1];
    const float* W1  = (const float*)d_in[2];
    const float* b1  = (const float*)d_in[3];
    const float* W2  = (const float*)d_in[4];
    const float* b2  = (const float*)d_in[5];
    float* outp = (float*)d_out;

    fused_anchor_mlp<<<NB / 8, 512, 0, stream>>>(Gl, anc, W1, b1, W2, b2, outp);
}

// Round 6
// 138.226 us; speedup vs baseline: 2.9030x; 1.0717x over previous
//
#include <hip/hip_runtime.h>
#include <hip/hip_bf16.h>
#include <math.h>

#define NB   32768
#define NM   2048
#define NEMB 128
#define NK   8
#define TAU  0.3f
#define FLT_BIG 3.402823466e38f

typedef __attribute__((ext_vector_type(8))) short bf16x8;
typedef __attribute__((ext_vector_type(4))) float f32x4;

// tanh-form GELU: x * sigmoid(2*0.79788456*(x+0.044715 x^3)), branch-free.
// |dev vs exact erf-GELU| <= ~1e-3; well within 6.4e-2 budget.
__device__ __forceinline__ float gelu_tanh(float x) {
    const float x2 = x * x;
    const float u  = fmaf(0.044715f, x2, 1.0f);
    const float a  = x * u * (-2.3022082f);          // -2*0.79788456*log2(e)
    const float e  = __builtin_amdgcn_exp2f(a);      // exp(-2t)
    const float r  = __builtin_amdgcn_rcpf(e + 1.0f);
    return x * r;                                    // x * sigmoid(2t)
}
// f32 pair -> packed bf16 (RNE): (bf16(hi)<<16)|bf16(lo), 1 v_cvt_pk_bf16_f32
__device__ __forceinline__ unsigned pack2(float lo, float hi) {
    __hip_bfloat162 b = __float22bfloat162_rn(make_float2(lo, hi));
    return *reinterpret_cast<unsigned*>(&b);
}

// DPP helpers (compile-time ctrl): quad_perm xor1=0xB1, xor2=0x4E,
// row_half_mirror(^7)=0x141, row_mirror(^15)=0x140
template<int CTRL>
__device__ __forceinline__ unsigned dpp_umin(unsigned v) {
    const unsigned t = (unsigned)__builtin_amdgcn_update_dpp(0, (int)v, CTRL, 0xF, 0xF, true);
    return v < t ? v : t;
}
template<int CTRL>
__device__ __forceinline__ float dpp_fadd(float v) {
    const float t = __int_as_float(__builtin_amdgcn_update_dpp(0, __float_as_int(v), CTRL, 0xF, 0xF, true));
    return v + t;
}

// exact top-8 extraction over the union of per-lane sorted lists.
// key = float bits of d (d>=0 -> u32-monotone). Returns this lane's pop count.
template<int DEPTH>
__device__ __forceinline__ int extract8(float (&ld)[DEPTH], unsigned (&lp)[DEPTH],
                                        float (&td)[8], unsigned (&tp)[8], const int lane) {
    int pops = 0;
#pragma unroll
    for (int k = 0; k < 8; ++k) {
        const unsigned key = __float_as_uint(ld[0]);
        unsigned m = key;
        m = dpp_umin<0xB1>(m);  m = dpp_umin<0x4E>(m);
        m = dpp_umin<0x141>(m); m = dpp_umin<0x140>(m);
        { unsigned t = __shfl_xor(m, 16); m = m < t ? m : t;
          t = __shfl_xor(m, 32);          m = m < t ? m : t; }
        const unsigned long long mk = __ballot(key == m);
        const int src = __ffsll(mk) - 1;          // lowest lane holding the min
        td[k] = __uint_as_float(m);
        tp[k] = __shfl(lp[0], src);
        if (lane == src) {
#pragma unroll
            for (int j = 0; j < DEPTH - 1; ++j) { ld[j] = ld[j + 1]; lp[j] = lp[j + 1]; }
            ld[DEPTH - 1] = FLT_BIG;
            ++pops;
        }
    }
    return pops;
}

// ---------------------------------------------------------------------------
// Fused kernel, 512 threads = 8 waves = 8 rows/block.
// Phase 1: stream anchors (nontemporal), UNCONDITIONAL per-lane sorted top-3
//   (fmin/fmed3 values + packed-bf16 (x,y) payload), DPP-argmin extraction x8,
//   full-rescan fallback when any lane had all 3 entries popped (P~1.4%/row).
// Phase 2: softmax weights -> layer1 tanh-GELU -> bf16 h1 pair tile (LDS,
//   swizzled) -> mfma_f32_16x16x32_bf16 (A=W2 bf16 LDS) -> fused epilogue
//   with DPP 8-lane k-reduction. Row-pairing: B cols 0..7 even row, 8..15 odd.
// ---------------------------------------------------------------------------
__global__ void __launch_bounds__(512, 6) fused_anchor_mlp(
    const float* __restrict__ Gl, const float* __restrict__ ancL,
    const float* __restrict__ W1, const float* __restrict__ b1,
    const float* __restrict__ W2, const float* __restrict__ b2,
    float* __restrict__ out)
{
    __shared__ uint4  w2s[2048];      // 128 rows x 16 slots bf16x8, 32 KB
    __shared__ uint4  h1s4[1024];     // 4 pairs x 16 k-rows x 16 slots, 16 KB
    __shared__ float4 b2s4[32];       // 512 B
    __shared__ float  wts[8][8];      // softmax weights per row

    const int tid  = threadIdx.x;
    const int wave = tid >> 6;
    const int lane = tid & 63;
    const int pair = wave >> 1;
    const int half = wave & 1;
    const int rowbase = blockIdx.x << 3;
    const int row  = rowbase + wave;

    // --- stage W2 (f32 -> bf16, phys_slot = slot ^ (row&7)) ---
    {
        const float4* w2f = reinterpret_cast<const float4*>(W2);
        for (int i = tid; i < 2048; i += 512) {
            const float4 lo = w2f[i * 2], hi = w2f[i * 2 + 1];
            uint4 u;
            u.x = pack2(lo.x, lo.y); u.y = pack2(lo.z, lo.w);
            u.z = pack2(hi.x, hi.y); u.w = pack2(hi.z, hi.w);
            w2s[(i & ~15) | ((i & 15) ^ ((i >> 4) & 7))] = u;
        }
        if (tid < 32) b2s4[tid] = reinterpret_cast<const float4*>(b2)[tid];
    }
    // single __syncthreads below (after h1 writes) covers all staging

    // --- phase 1: stream anchors, unconditional per-lane sorted top-3 ---
    const float2 g = reinterpret_cast<const float2*>(Gl)[row];
    const f32x4* a4 = reinterpret_cast<const f32x4*>(ancL) + (size_t)row * (NM / 2);

    float    bd[3];
    unsigned bp[3];
#pragma unroll
    for (int i = 0; i < 3; ++i) { bd[i] = FLT_BIG; bp[i] = 0u; }

    auto ins3 = [&](float d, unsigned p) {
        const bool c0 = d < bd[0], c1 = d < bd[1], c2 = d < bd[2];
        // values via med3 (sorted-insert identity), payload via cndmask
        const float n2 = __builtin_amdgcn_fmed3f(d, bd[1], bd[2]);
        const float n1 = __builtin_amdgcn_fmed3f(d, bd[0], bd[1]);
        const float n0 = fminf(d, bd[0]);
        bp[2] = c1 ? bp[1] : (c2 ? p : bp[2]);
        bp[1] = c0 ? bp[0] : (c1 ? p : bp[1]);
        bp[0] = c0 ? p : bp[0];
        bd[2] = n2; bd[1] = n1; bd[0] = n0;
    };

    f32x4 v = __builtin_nontemporal_load(&a4[lane]);
#pragma unroll 4
    for (int it = 0; it < 16; ++it) {
        f32x4 vn;
        if (it < 15) vn = __builtin_nontemporal_load(&a4[(it + 1) * 64 + lane]);
        const float dx0 = v.x - g.x, dy0 = v.y - g.y;
        const float dx1 = v.z - g.x, dy1 = v.w - g.y;
        // bit-identical to numpy: no fma contraction
        const float d0 = __fadd_rn(__fmul_rn(dx0, dx0), __fmul_rn(dy0, dy0));
        const float d1 = __fadd_rn(__fmul_rn(dx1, dx1), __fmul_rn(dy1, dy1));
        ins3(d0, pack2(v.x, v.y));
        ins3(d1, pack2(v.z, v.w));
        if (it < 15) v = vn;
    }

    // --- extraction: 8 rounds of DPP-argmin over lane heads ---
    float    td[8];
    unsigned tp[8];
    const int pops = extract8<3>(bd, bp, td, tp, lane);

    // --- exactness fallback (P~1.4%/row): some lane had all 3 popped ---
    if (__ballot(pops == 3)) {
        float    fd[8];
        unsigned fp[8];
#pragma unroll
        for (int i = 0; i < 8; ++i) { fd[i] = FLT_BIG; fp[i] = 0u; }
        for (int it = 0; it < 16; ++it) {
            const f32x4 vv = a4[it * 64 + lane];
#pragma unroll
            for (int h = 0; h < 2; ++h) {
                const float ax = h ? vv.z : vv.x;
                const float ay = h ? vv.w : vv.y;
                const float ddx = ax - g.x, ddy = ay - g.y;
                const float d = __fadd_rn(__fmul_rn(ddx, ddx), __fmul_rn(ddy, ddy));
                if (d < fd[7]) {
                    const unsigned p = pack2(ax, ay);
#pragma unroll
                    for (int j = 7; j >= 1; --j) {
                        const bool s1 = fd[j - 1] > d;
                        const bool s2 = fd[j] > d;
                        const float    nd = s1 ? fd[j - 1] : (s2 ? d : fd[j]);
                        const unsigned np = s1 ? fp[j - 1] : (s2 ? p : fp[j]);
                        fd[j] = nd; fp[j] = np;
                    }
                    if (fd[0] > d) { fd[0] = d; fp[0] = p; }
                }
            }
        }
        (void)extract8<8>(fd, fp, td, tp, lane);
    }

    // --- softmax(d2/tau); publish weights for the pair epilogue ---
    const float mx = td[7];
    float ek[8], ssum = 0.f;
#pragma unroll
    for (int k = 0; k < 8; ++k) { ek[k] = __expf((td[k] - mx) * (1.0f / TAU)); ssum += ek[k]; }
    const float inv = 1.0f / ssum;
    float wv = 0.f;
#pragma unroll
    for (int k = 0; k < 8; ++k) wv = (lane == k) ? ek[k] * inv : wv;
    if (lane < 8) wts[wave][lane] = wv;

    // --- layer 1: lane owns e0=2*lane, e1=2*lane+1; write to pair tile ---
    const float4 w1v = reinterpret_cast<const float4*>(W1)[lane];
    const float2 b1v = reinterpret_cast<const float2*>(b1)[lane];
    unsigned* h1w = reinterpret_cast<unsigned*>(h1s4 + (pair << 8));
#pragma unroll
    for (int k = 0; k < 8; ++k) {
        const unsigned pk = tp[k];
        const float ax = __uint_as_float(pk << 16);          // bf16 -> f32 exact
        const float ay = __uint_as_float(pk & 0xFFFF0000u);
        const float x0 = fmaf(ax, w1v.x, fmaf(ay, w1v.y, b1v.x));
        const float x1 = fmaf(ax, w1v.z, fmaf(ay, w1v.w, b1v.y));
        const int r = (half << 3) + k;   // row in pair tile; swizzle key = r&7 = k
        h1w[(r << 6) + ((((lane >> 2) ^ k) << 2) | (lane & 3))] = pack2(gelu_tanh(x0), gelu_tanh(x1));
    }
    __syncthreads();

    // --- B fragments from pair tile: col n = lane&15 (0..7 even, 8..15 odd) ---
    const uint4* h1b = h1s4 + (pair << 8);
    const int bslot = lane >> 4, bxor = lane & 7, brow = (lane & 15) * 16;
    bf16x8 bq0 = __builtin_bit_cast(bf16x8, h1b[brow + (( 0 + bslot) ^ bxor)]);
    bf16x8 bq1 = __builtin_bit_cast(bf16x8, h1b[brow + (( 4 + bslot) ^ bxor)]);
    bf16x8 bq2 = __builtin_bit_cast(bf16x8, h1b[brow + (( 8 + bslot) ^ bxor)]);
    bf16x8 bq3 = __builtin_bit_cast(bf16x8, h1b[brow + ((12 + bslot) ^ bxor)]);

    // weight for this lane's D column
    const float wsel = wts[(pair << 1) | ((lane >> 3) & 1)][lane & 7];

    // --- MFMA: this wave does f-tiles half*4 .. half*4+3 for BOTH rows ---
#pragma unroll 2
    for (int i = 0; i < 4; ++i) {
        const int ft = (half << 2) + i;
        const int arow = (ft * 16 + (lane & 15)) * 16;
        f32x4 acc = {0.f, 0.f, 0.f, 0.f};
        acc = __builtin_amdgcn_mfma_f32_16x16x32_bf16(
                  __builtin_bit_cast(bf16x8, w2s[arow + (( 0 + bslot) ^ bxor)]), bq0, acc, 0, 0, 0);
        acc = __builtin_amdgcn_mfma_f32_16x16x32_bf16(
                  __builtin_bit_cast(bf16x8, w2s[arow + (( 4 + bslot) ^ bxor)]), bq1, acc, 0, 0, 0);
        acc = __builtin_amdgcn_mfma_f32_16x16x32_bf16(
                  __builtin_bit_cast(bf16x8, w2s[arow + (( 8 + bslot) ^ bxor)]), bq2, acc, 0, 0, 0);
        acc = __builtin_amdgcn_mfma_f32_16x16x32_bf16(
                  __builtin_bit_cast(bf16x8, w2s[arow + ((12 + bslot) ^ bxor)]), bq3, acc, 0, 0, 0);

        // D: row f = ft*16 + (lane>>4)*4 + j, col = lane&15
        const float4 b2v = b2s4[ft * 4 + (lane >> 4)];
        float s0 = gelu_tanh(acc[0] + b2v.x) * wsel;
        float s1 = gelu_tanh(acc[1] + b2v.y) * wsel;
        float s2 = gelu_tanh(acc[2] + b2v.z) * wsel;
        float s3 = gelu_tanh(acc[3] + b2v.w) * wsel;
        // sum over the 8 k-slots (lanes sharing lane&~7) via DPP adds
        s0 = dpp_fadd<0xB1>(s0); s0 = dpp_fadd<0x4E>(s0); s0 = dpp_fadd<0x141>(s0);
        s1 = dpp_fadd<0xB1>(s1); s1 = dpp_fadd<0x4E>(s1); s1 = dpp_fadd<0x141>(s1);
        s2 = dpp_fadd<0xB1>(s2); s2 = dpp_fadd<0x4E>(s2); s2 = dpp_fadd<0x141>(s2);
        s3 = dpp_fadd<0xB1>(s3); s3 = dpp_fadd<0x4E>(s3); s3 = dpp_fadd<0x141>(s3);
        if ((lane & 7) == 0) {
            const int which = (lane >> 3) & 1;   // 0 = row even, 1 = row odd
            const size_t ob = (size_t)(rowbase + (pair << 1) + which) * NEMB
                              + ft * 16 + ((lane >> 4) << 2);
            *reinterpret_cast<float4*>(&out[ob]) = make_float4(s0, s1, s2, s3);
        }
    }
}

extern "C" void kernel_launch(void* const* d_in, const int* in_sizes, int n_in,
                              void* d_out, int out_size, void* d_ws, size_t ws_size,
                              hipStream_t stream)
{
    const float* Gl  = (const float*)d_in[0];
    const float* anc = (const float*)d_in[1];
    const float* W1  = (const float*)d_in[2];
    const float* b1  = (const float*)d_in[3];
    const float* W2  = (const float*)d_in[4];
    const float* b2  = (const float*)d_in[5];
    float* outp = (float*)d_out;

    fused_anchor_mlp<<<NB / 8, 512, 0, stream>>>(Gl, anc, W1, b1, W2, b2, outp);
}

// Round 7
// 133.294 us; speedup vs baseline: 3.0104x; 1.0370x over previous
//
#include <hip/hip_runtime.h>
#include <hip/hip_bf16.h>
#include <math.h>

#define NB   32768
#define NM   2048
#define NEMB 128
#define NK   8
#define TAU  0.3f
#define FLT_BIG 3.402823466e38f

typedef __attribute__((ext_vector_type(8))) short bf16x8;
typedef __attribute__((ext_vector_type(4))) float f32x4;

// tanh-form GELU: x * sigmoid(2*0.79788456*(x+0.044715 x^3)), branch-free.
__device__ __forceinline__ float gelu_tanh(float x) {
    const float x2 = x * x;
    const float u  = fmaf(0.044715f, x2, 1.0f);
    const float a  = x * u * (-2.3022082f);          // -2*0.79788456*log2(e)
    const float e  = __builtin_amdgcn_exp2f(a);      // exp(-2t)
    const float r  = __builtin_amdgcn_rcpf(e + 1.0f);
    return x * r;                                    // x * sigmoid(2t)
}
// f32 pair -> packed bf16 (RNE): (bf16(hi)<<16)|bf16(lo), 1 v_cvt_pk_bf16_f32
__device__ __forceinline__ unsigned pack2(float lo, float hi) {
    __hip_bfloat162 b = __float22bfloat162_rn(make_float2(lo, hi));
    return *reinterpret_cast<unsigned*>(&b);
}

// DPP helpers: quad_perm xor1=0xB1, xor2=0x4E, row_half_mirror=0x141, row_mirror=0x140
template<int CTRL>
__device__ __forceinline__ unsigned dpp_umin(unsigned v) {
    const unsigned t = (unsigned)__builtin_amdgcn_update_dpp(0, (int)v, CTRL, 0xF, 0xF, true);
    return v < t ? v : t;
}
template<int CTRL>
__device__ __forceinline__ float dpp_fadd(float v) {
    const float t = __int_as_float(__builtin_amdgcn_update_dpp(0, __float_as_int(v), CTRL, 0xF, 0xF, true));
    return v + t;
}

// exact top-8 extraction over the union of per-lane sorted lists.
template<int DEPTH>
__device__ __forceinline__ int extract8(float (&ld)[DEPTH], unsigned (&lp)[DEPTH],
                                        float (&td)[8], unsigned (&tp)[8], const int lane) {
    int pops = 0;
#pragma unroll
    for (int k = 0; k < 8; ++k) {
        const unsigned key = __float_as_uint(ld[0]);
        unsigned m = key;
        m = dpp_umin<0xB1>(m);  m = dpp_umin<0x4E>(m);
        m = dpp_umin<0x141>(m); m = dpp_umin<0x140>(m);
        { unsigned t = __shfl_xor(m, 16); m = m < t ? m : t;
          t = __shfl_xor(m, 32);          m = m < t ? m : t; }
        const unsigned long long mk = __ballot(key == m);
        const int src = __ffsll(mk) - 1;          // lowest lane holding the min
        td[k] = __uint_as_float(m);
        tp[k] = __shfl(lp[0], src);
        if (lane == src) {
#pragma unroll
            for (int j = 0; j < DEPTH - 1; ++j) { ld[j] = ld[j + 1]; lp[j] = lp[j + 1]; }
            ld[DEPTH - 1] = FLT_BIG;
            ++pops;
        }
    }
    return pops;
}

// ---------------------------------------------------------------------------
// Fused kernel, 512 threads = 8 waves = 8 rows/block.
// Phase 1: stream anchors with a 3-deep rolling load pipeline (3 nontemporal
//   loads in flight per wave -> hides HBM latency at ~11-24 waves/CU),
//   unconditional per-lane sorted top-3 (fmed3 + packed-bf16 payload),
//   DPP-argmin extraction x8, full-rescan fallback (P~1.4%/row).
// Phase 2: softmax weights -> layer1 tanh-GELU -> bf16 h1 pair tile (LDS,
//   swizzled) -> mfma_f32_16x16x32_bf16 (A=W2 bf16 LDS) -> fused epilogue
//   with DPP 8-lane k-reduction. Row-pairing: B cols 0..7 even row, 8..15 odd.
// ---------------------------------------------------------------------------
__global__ void __launch_bounds__(512, 6) fused_anchor_mlp(
    const float* __restrict__ Gl, const float* __restrict__ ancL,
    const float* __restrict__ W1, const float* __restrict__ b1,
    const float* __restrict__ W2, const float* __restrict__ b2,
    float* __restrict__ out)
{
    __shared__ uint4  w2s[2048];      // 128 rows x 16 slots bf16x8, 32 KB
    __shared__ uint4  h1s4[1024];     // 4 pairs x 16 k-rows x 16 slots, 16 KB
    __shared__ float4 b2s4[32];       // 512 B
    __shared__ float  wts[8][8];      // softmax weights per row

    const int tid  = threadIdx.x;
    const int wave = tid >> 6;
    const int lane = tid & 63;
    const int pair = wave >> 1;
    const int half = wave & 1;
    const int rowbase = blockIdx.x << 3;
    const int row  = rowbase + wave;

    // --- stage W2 (f32 -> bf16, phys_slot = slot ^ (row&7)) ---
    {
        const float4* w2f = reinterpret_cast<const float4*>(W2);
        for (int i = tid; i < 2048; i += 512) {
            const float4 lo = w2f[i * 2], hi = w2f[i * 2 + 1];
            uint4 u;
            u.x = pack2(lo.x, lo.y); u.y = pack2(lo.z, lo.w);
            u.z = pack2(hi.x, hi.y); u.w = pack2(hi.z, hi.w);
            w2s[(i & ~15) | ((i & 15) ^ ((i >> 4) & 7))] = u;
        }
        if (tid < 32) b2s4[tid] = reinterpret_cast<const float4*>(b2)[tid];
    }
    // single __syncthreads below (after h1 writes) covers all staging

    // --- phase 1: stream anchors, 3-deep rolling prefetch, top-3/lane ---
    const float2 g = reinterpret_cast<const float2*>(Gl)[row];
    const f32x4* a4 = reinterpret_cast<const f32x4*>(ancL) + (size_t)row * (NM / 2);

    float    bd[3];
    unsigned bp[3];
#pragma unroll
    for (int i = 0; i < 3; ++i) { bd[i] = FLT_BIG; bp[i] = 0u; }

    auto ins3 = [&](float d, unsigned p) {
        const bool c0 = d < bd[0], c1 = d < bd[1], c2 = d < bd[2];
        const float n2 = __builtin_amdgcn_fmed3f(d, bd[1], bd[2]);
        const float n1 = __builtin_amdgcn_fmed3f(d, bd[0], bd[1]);
        const float n0 = fminf(d, bd[0]);
        bp[2] = c1 ? bp[1] : (c2 ? p : bp[2]);
        bp[1] = c0 ? bp[0] : (c1 ? p : bp[1]);
        bp[0] = c0 ? p : bp[0];
        bd[2] = n2; bd[1] = n1; bd[0] = n0;
    };

    f32x4 buf[3];
#pragma unroll
    for (int j = 0; j < 3; ++j) buf[j] = __builtin_nontemporal_load(&a4[j * 64 + lane]);

#pragma unroll
    for (int it = 0; it < 16; ++it) {
        const int slot = it % 3;                 // static after full unroll
        const f32x4 v = buf[slot];
        if (it + 3 < 16)
            buf[slot] = __builtin_nontemporal_load(&a4[(it + 3) * 64 + lane]);
        const float dx0 = v.x - g.x, dy0 = v.y - g.y;
        const float dx1 = v.z - g.x, dy1 = v.w - g.y;
        // bit-identical to numpy: no fma contraction
        const float d0 = __fadd_rn(__fmul_rn(dx0, dx0), __fmul_rn(dy0, dy0));
        const float d1 = __fadd_rn(__fmul_rn(dx1, dx1), __fmul_rn(dy1, dy1));
        ins3(d0, pack2(v.x, v.y));
        ins3(d1, pack2(v.z, v.w));
    }

    // --- extraction: 8 rounds of DPP-argmin over lane heads ---
    float    td[8];
    unsigned tp[8];
    const int pops = extract8<3>(bd, bp, td, tp, lane);

    // --- exactness fallback (P~1.4%/row): some lane had all 3 popped ---
    if (__ballot(pops == 3)) {
        float    fd[8];
        unsigned fp[8];
#pragma unroll
        for (int i = 0; i < 8; ++i) { fd[i] = FLT_BIG; fp[i] = 0u; }
        for (int it = 0; it < 16; ++it) {
            const f32x4 vv = a4[it * 64 + lane];
#pragma unroll
            for (int h = 0; h < 2; ++h) {
                const float ax = h ? vv.z : vv.x;
                const float ay = h ? vv.w : vv.y;
                const float ddx = ax - g.x, ddy = ay - g.y;
                const float d = __fadd_rn(__fmul_rn(ddx, ddx), __fmul_rn(ddy, ddy));
                if (d < fd[7]) {
                    const unsigned p = pack2(ax, ay);
#pragma unroll
                    for (int j = 7; j >= 1; --j) {
                        const bool s1 = fd[j - 1] > d;
                        const bool s2 = fd[j] > d;
                        const float    nd = s1 ? fd[j - 1] : (s2 ? d : fd[j]);
                        const unsigned np = s1 ? fp[j - 1] : (s2 ? p : fp[j]);
                        fd[j] = nd; fp[j] = np;
                    }
                    if (fd[0] > d) { fd[0] = d; fp[0] = p; }
                }
            }
        }
        (void)extract8<8>(fd, fp, td, tp, lane);
    }

    // --- softmax(d2/tau); publish weights for the pair epilogue ---
    const float mx = td[7];
    float ek[8], ssum = 0.f;
#pragma unroll
    for (int k = 0; k < 8; ++k) { ek[k] = __expf((td[k] - mx) * (1.0f / TAU)); ssum += ek[k]; }
    const float inv = 1.0f / ssum;
    float wv = 0.f;
#pragma unroll
    for (int k = 0; k < 8; ++k) wv = (lane == k) ? ek[k] * inv : wv;
    if (lane < 8) wts[wave][lane] = wv;

    // --- layer 1: lane owns e0=2*lane, e1=2*lane+1; write to pair tile ---
    const float4 w1v = reinterpret_cast<const float4*>(W1)[lane];
    const float2 b1v = reinterpret_cast<const float2*>(b1)[lane];
    unsigned* h1w = reinterpret_cast<unsigned*>(h1s4 + (pair << 8));
#pragma unroll
    for (int k = 0; k < 8; ++k) {
        const unsigned pk = tp[k];
        const float ax = __uint_as_float(pk << 16);          // bf16 -> f32 exact
        const float ay = __uint_as_float(pk & 0xFFFF0000u);
        const float x0 = fmaf(ax, w1v.x, fmaf(ay, w1v.y, b1v.x));
        const float x1 = fmaf(ax, w1v.z, fmaf(ay, w1v.w, b1v.y));
        const int r = (half << 3) + k;   // row in pair tile; swizzle key = r&7 = k
        h1w[(r << 6) + ((((lane >> 2) ^ k) << 2) | (lane & 3))] = pack2(gelu_tanh(x0), gelu_tanh(x1));
    }
    __syncthreads();

    // --- B fragments from pair tile: col n = lane&15 (0..7 even, 8..15 odd) ---
    const uint4* h1b = h1s4 + (pair << 8);
    const int bslot = lane >> 4, bxor = lane & 7, brow = (lane & 15) * 16;
    bf16x8 bq0 = __builtin_bit_cast(bf16x8, h1b[brow + (( 0 + bslot) ^ bxor)]);
    bf16x8 bq1 = __builtin_bit_cast(bf16x8, h1b[brow + (( 4 + bslot) ^ bxor)]);
    bf16x8 bq2 = __builtin_bit_cast(bf16x8, h1b[brow + (( 8 + bslot) ^ bxor)]);
    bf16x8 bq3 = __builtin_bit_cast(bf16x8, h1b[brow + ((12 + bslot) ^ bxor)]);

    // weight for this lane's D column
    const float wsel = wts[(pair << 1) | ((lane >> 3) & 1)][lane & 7];

    // --- MFMA: this wave does f-tiles half*4 .. half*4+3 for BOTH rows ---
#pragma unroll 2
    for (int i = 0; i < 4; ++i) {
        const int ft = (half << 2) + i;
        const int arow = (ft * 16 + (lane & 15)) * 16;
        f32x4 acc = {0.f, 0.f, 0.f, 0.f};
        acc = __builtin_amdgcn_mfma_f32_16x16x32_bf16(
                  __builtin_bit_cast(bf16x8, w2s[arow + (( 0 + bslot) ^ bxor)]), bq0, acc, 0, 0, 0);
        acc = __builtin_amdgcn_mfma_f32_16x16x32_bf16(
                  __builtin_bit_cast(bf16x8, w2s[arow + (( 4 + bslot) ^ bxor)]), bq1, acc, 0, 0, 0);
        acc = __builtin_amdgcn_mfma_f32_16x16x32_bf16(
                  __builtin_bit_cast(bf16x8, w2s[arow + (( 8 + bslot) ^ bxor)]), bq2, acc, 0, 0, 0);
        acc = __builtin_amdgcn_mfma_f32_16x16x32_bf16(
                  __builtin_bit_cast(bf16x8, w2s[arow + ((12 + bslot) ^ bxor)]), bq3, acc, 0, 0, 0);

        // D: row f = ft*16 + (lane>>4)*4 + j, col = lane&15
        const float4 b2v = b2s4[ft * 4 + (lane >> 4)];
        float s0 = gelu_tanh(acc[0] + b2v.x) * wsel;
        float s1 = gelu_tanh(acc[1] + b2v.y) * wsel;
        float s2 = gelu_tanh(acc[2] + b2v.z) * wsel;
        float s3 = gelu_tanh(acc[3] + b2v.w) * wsel;
        // sum over the 8 k-slots (lanes sharing lane&~7) via DPP adds
        s0 = dpp_fadd<0xB1>(s0); s0 = dpp_fadd<0x4E>(s0); s0 = dpp_fadd<0x141>(s0);
        s1 = dpp_fadd<0xB1>(s1); s1 = dpp_fadd<0x4E>(s1); s1 = dpp_fadd<0x141>(s1);
        s2 = dpp_fadd<0xB1>(s2); s2 = dpp_fadd<0x4E>(s2); s2 = dpp_fadd<0x141>(s2);
        s3 = dpp_fadd<0xB1>(s3); s3 = dpp_fadd<0x4E>(s3); s3 = dpp_fadd<0x141>(s3);
        if ((lane & 7) == 0) {
            const int which = (lane >> 3) & 1;   // 0 = row even, 1 = row odd
            const size_t ob = (size_t)(rowbase + (pair << 1) + which) * NEMB
                              + ft * 16 + ((lane >> 4) << 2);
            *reinterpret_cast<float4*>(&out[ob]) = make_float4(s0, s1, s2, s3);
        }
    }
}

extern "C" void kernel_launch(void* const* d_in, const int* in_sizes, int n_in,
                              void* d_out, int out_size, void* d_ws, size_t ws_size,
                              hipStream_t stream)
{
    const float* Gl  = (const float*)d_in[0];
    const float* anc = (const float*)d_in[1];
    const float* W1  = (const float*)d_in[2];
    const float* b1  = (const float*)d_in[3];
    const float* W2  = (const float*)d_in[4];
    const float* b2  = (const float*)d_in[5];
    float* outp = (float*)d_out;

    fused_anchor_mlp<<<NB / 8, 512, 0, stream>>>(Gl, anc, W1, b1, W2, b2, outp);
}